// Round 8
// baseline (6734.386 us; speedup 1.0000x reference)
//
#include <hip/hip_runtime.h>
#include <math.h>

#define BB   64
#define NIN  512
#define NH   512
#define TT   512

typedef _Float16 half2_t __attribute__((ext_vector_type(2)));
typedef _Float16 half8_t __attribute__((ext_vector_type(8)));
typedef float    f32x4  __attribute__((ext_vector_type(4)));

__device__ __forceinline__ unsigned pk16(float x, float y) {
    unsigned lo = (unsigned)__builtin_bit_cast(unsigned short, (_Float16)x);
    unsigned hi = (unsigned)__builtin_bit_cast(unsigned short, (_Float16)y);
    return lo | (hi << 16);
}

__device__ __forceinline__ float tanh_fast(float x) {
    float ax = __builtin_fabsf(x);
    float e  = __builtin_amdgcn_exp2f(-2.885390082f * ax);   // exp(-2|x|)
    float r  = (1.0f - e) * __builtin_amdgcn_rcpf(1.0f + e);
    return __builtin_copysignf(r, x);
}

__device__ __forceinline__ uint4 mkbfrag(const float* W, int kb, int c) {
    uint4 v;
    v.x = pk16(W[(size_t)(kb + 0) * NH + c], W[(size_t)(kb + 1) * NH + c]);
    v.y = pk16(W[(size_t)(kb + 2) * NH + c], W[(size_t)(kb + 3) * NH + c]);
    v.z = pk16(W[(size_t)(kb + 4) * NH + c], W[(size_t)(kb + 5) * NH + c]);
    v.w = pk16(W[(size_t)(kb + 6) * NH + c], W[(size_t)(kb + 7) * NH + c]);
    return v;
}

__device__ __forceinline__ f32x4 mfma16(half8_t A, uint4 B, f32x4 C) {
    return __builtin_amdgcn_mfma_f32_16x16x32_f16(
        A, __builtin_bit_cast(half8_t, B), C, 0, 0, 0);
}

// ---------------------------------------------------------------------------
// K0: pack X and Wax into half2-pair dwords; also zero the scan's exchange
// buffers (rem + flags) so replayed graphs always start clean.
// ---------------------------------------------------------------------------
#define NX4 (BB * (NIN / 2) * (TT / 4))
#define NW4 ((NIN / 2) * (NH / 4))
#define REM_DW (BB * 2 * (NH / 2))          // 32768 dwords (u16[BB][2][512])
#define FLG_DW (BB * 2 * 32)                // 4096 dwords (padded flags)
#define NZ4 ((REM_DW + FLG_DW) / 4)         // 9216 uint4 zero units

__global__ __launch_bounds__(256) void pack_f16(
    const float* __restrict__ X, const float* __restrict__ Wax,
    unsigned* __restrict__ Xp, unsigned* __restrict__ Wp,
    unsigned* __restrict__ zb)
{
    const int gid = blockIdx.x * 256 + threadIdx.x;
    if (gid < NX4) {
        const int t4 = gid & (TT / 4 - 1);
        const int pr = gid >> 7;
        const int j  = pr & (NIN / 2 - 1);
        const int b  = pr >> 8;
        float4 r0 = *(const float4*)&X[((size_t)b * NIN + 2 * j    ) * TT + t4 * 4];
        float4 r1 = *(const float4*)&X[((size_t)b * NIN + 2 * j + 1) * TT + t4 * 4];
        uint4 o;
        o.x = pk16(r0.x, r1.x); o.y = pk16(r0.y, r1.y);
        o.z = pk16(r0.z, r1.z); o.w = pk16(r0.w, r1.w);
        *(uint4*)&Xp[(size_t)pr * TT + t4 * 4] = o;
    } else if (gid < NX4 + NW4) {
        const int g = gid - NX4;
        const int h4 = g & (NH / 4 - 1);
        const int j  = g >> 7;
        float4 r0 = *(const float4*)&Wax[((size_t)(2 * j    )) * NH + h4 * 4];
        float4 r1 = *(const float4*)&Wax[((size_t)(2 * j + 1)) * NH + h4 * 4];
        uint4 o;
        o.x = pk16(r0.x, r1.x); o.y = pk16(r0.y, r1.y);
        o.z = pk16(r0.z, r1.z); o.w = pk16(r0.w, r1.w);
        *(uint4*)&Wp[(size_t)j * NH + h4 * 4] = o;
    } else {
        const int g2 = gid - NX4 - NW4;
        if (g2 < NZ4) {
            uint4 z = {};
            *(uint4*)&zb[(size_t)g2 * 4] = z;
        }
    }
}

// ---------------------------------------------------------------------------
// K1' (MFMA, packed inputs) — unchanged, verified.
// ---------------------------------------------------------------------------
__global__ __launch_bounds__(256) void inp_proj_mfma_pk(
    const unsigned* __restrict__ Xp, const unsigned* __restrict__ Wp,
    const float* __restrict__ bx, const float* __restrict__ ba,
    float* __restrict__ out)
{
    __shared__ unsigned Xsp[16][132];
    __shared__ unsigned Wsp[16][132];

    const int b   = blockIdx.z;
    const int t0  = blockIdx.y * 128;
    const int h0  = blockIdx.x * 128;
    const int tid = threadIdx.x;
    const int lane = tid & 63;
    const int wid  = tid >> 6;
    const int wm   = wid >> 1;
    const int wn   = wid & 1;
    const int q    = lane >> 4;
    const int r16  = lane & 15;

    const int lr = tid >> 4;
    const int lc = (tid & 15) * 8;

    const unsigned* Xb = Xp + (size_t)b * (NIN / 2) * TT;

    f32x4 acc[4][4] = {};

    for (int p0 = 0; p0 < NIN / 2; p0 += 16) {
        const unsigned* Arow = &Xb[(size_t)(p0 + lr) * TT + t0 + lc];
        const unsigned* Brow = &Wp[(size_t)(p0 + lr) * NH + h0 + lc];
        uint4 xa = *(const uint4*)&Arow[0];
        uint4 xb = *(const uint4*)&Arow[4];
        uint4 wa = *(const uint4*)&Brow[0];
        uint4 wb = *(const uint4*)&Brow[4];

        __syncthreads();
        *(uint4*)&Xsp[lr][lc]     = xa;
        *(uint4*)&Xsp[lr][lc + 4] = xb;
        *(uint4*)&Wsp[lr][lc]     = wa;
        *(uint4*)&Wsp[lr][lc + 4] = wb;
        __syncthreads();

        uint4 af[4], bf[4];
#pragma unroll
        for (int mt = 0; mt < 4; ++mt) {
            const int tc = wm * 64 + mt * 16 + r16;
            af[mt].x = Xsp[4 * q + 0][tc];
            af[mt].y = Xsp[4 * q + 1][tc];
            af[mt].z = Xsp[4 * q + 2][tc];
            af[mt].w = Xsp[4 * q + 3][tc];
        }
#pragma unroll
        for (int nt = 0; nt < 4; ++nt) {
            const int hc = wn * 64 + nt * 16 + r16;
            bf[nt].x = Wsp[4 * q + 0][hc];
            bf[nt].y = Wsp[4 * q + 1][hc];
            bf[nt].z = Wsp[4 * q + 2][hc];
            bf[nt].w = Wsp[4 * q + 3][hc];
        }
#pragma unroll
        for (int mt = 0; mt < 4; ++mt)
#pragma unroll
            for (int nt = 0; nt < 4; ++nt)
                acc[mt][nt] = __builtin_amdgcn_mfma_f32_16x16x32_f16(
                    __builtin_bit_cast(half8_t, af[mt]),
                    __builtin_bit_cast(half8_t, bf[nt]),
                    acc[mt][nt], 0, 0, 0);
    }

#pragma unroll
    for (int nt = 0; nt < 4; ++nt) {
        const int h = h0 + wn * 64 + nt * 16 + r16;
        const float bias = bx[h] + ba[h];
#pragma unroll
        for (int mt = 0; mt < 4; ++mt) {
            const int trow = t0 + wm * 64 + mt * 16 + q * 4;
#pragma unroll
            for (int rr = 0; rr < 4; ++rr) {
                out[(size_t)(trow + rr) * (BB * NH) + (size_t)b * NH + h] =
                    acc[mt][nt][rr] + bias;
            }
        }
    }
}

// ---------------------------------------------------------------------------
// K1 fallback (f32 inputs) — used only if ws too small. Unchanged.
// ---------------------------------------------------------------------------
__global__ __launch_bounds__(256) void inp_proj_mfma(
    const float* __restrict__ X, const float* __restrict__ Wax,
    const float* __restrict__ bx, const float* __restrict__ ba,
    float* __restrict__ out)
{
    __shared__ unsigned Xsp[16][132];
    __shared__ unsigned Wsp[16][132];

    const int b   = blockIdx.z;
    const int t0  = blockIdx.y * 128;
    const int h0  = blockIdx.x * 128;
    const int tid = threadIdx.x;
    const int lane = tid & 63;
    const int wid  = tid >> 6;
    const int wm   = wid >> 1;
    const int wn   = wid & 1;
    const int q    = lane >> 4;
    const int r16  = lane & 15;

    const int lr = tid >> 4;
    const int lc = (tid & 15) * 8;

    const float* Xb = X + (size_t)b * NIN * TT;

    f32x4 acc[4][4] = {};

    for (int i0 = 0; i0 < NIN; i0 += 32) {
        const int k0 = i0 + 2 * lr, k1 = k0 + 1;
        float4 xa0 = *(const float4*)&Xb[(size_t)k0 * TT + t0 + lc];
        float4 xa1 = *(const float4*)&Xb[(size_t)k0 * TT + t0 + lc + 4];
        float4 xb0 = *(const float4*)&Xb[(size_t)k1 * TT + t0 + lc];
        float4 xb1 = *(const float4*)&Xb[(size_t)k1 * TT + t0 + lc + 4];
        float4 wa0 = *(const float4*)&Wax[(size_t)k0 * NH + h0 + lc];
        float4 wa1 = *(const float4*)&Wax[(size_t)k0 * NH + h0 + lc + 4];
        float4 wb0 = *(const float4*)&Wax[(size_t)k1 * NH + h0 + lc];
        float4 wb1 = *(const float4*)&Wax[(size_t)k1 * NH + h0 + lc + 4];

        uint4 xp0, xp1, wp0, wp1;
        xp0.x = pk16(xa0.x, xb0.x); xp0.y = pk16(xa0.y, xb0.y);
        xp0.z = pk16(xa0.z, xb0.z); xp0.w = pk16(xa0.w, xb0.w);
        xp1.x = pk16(xa1.x, xb1.x); xp1.y = pk16(xa1.y, xb1.y);
        xp1.z = pk16(xa1.z, xb1.z); xp1.w = pk16(xa1.w, xb1.w);
        wp0.x = pk16(wa0.x, wb0.x); wp0.y = pk16(wa0.y, wb0.y);
        wp0.z = pk16(wa0.z, wb0.z); wp0.w = pk16(wa0.w, wb0.w);
        wp1.x = pk16(wa1.x, wb1.x); wp1.y = pk16(wa1.y, wb1.y);
        wp1.z = pk16(wa1.z, wb1.z); wp1.w = pk16(wa1.w, wb1.w);

        __syncthreads();
        *(uint4*)&Xsp[lr][lc]     = xp0;
        *(uint4*)&Xsp[lr][lc + 4] = xp1;
        *(uint4*)&Wsp[lr][lc]     = wp0;
        *(uint4*)&Wsp[lr][lc + 4] = wp1;
        __syncthreads();

        uint4 af[4], bf[4];
#pragma unroll
        for (int mt = 0; mt < 4; ++mt) {
            const int tc = wm * 64 + mt * 16 + r16;
            af[mt].x = Xsp[4 * q + 0][tc];
            af[mt].y = Xsp[4 * q + 1][tc];
            af[mt].z = Xsp[4 * q + 2][tc];
            af[mt].w = Xsp[4 * q + 3][tc];
        }
#pragma unroll
        for (int nt = 0; nt < 4; ++nt) {
            const int hc = wn * 64 + nt * 16 + r16;
            bf[nt].x = Wsp[4 * q + 0][hc];
            bf[nt].y = Wsp[4 * q + 1][hc];
            bf[nt].z = Wsp[4 * q + 2][hc];
            bf[nt].w = Wsp[4 * q + 3][hc];
        }
#pragma unroll
        for (int mt = 0; mt < 4; ++mt)
#pragma unroll
            for (int nt = 0; nt < 4; ++nt)
                acc[mt][nt] = __builtin_amdgcn_mfma_f32_16x16x32_f16(
                    __builtin_bit_cast(half8_t, af[mt]),
                    __builtin_bit_cast(half8_t, bf[nt]),
                    acc[mt][nt], 0, 0, 0);
    }

#pragma unroll
    for (int nt = 0; nt < 4; ++nt) {
        const int h = h0 + wn * 64 + nt * 16 + r16;
        const float bias = bx[h] + ba[h];
#pragma unroll
        for (int mt = 0; mt < 4; ++mt) {
            const int trow = t0 + wm * 64 + mt * 16 + q * 4;
#pragma unroll
            for (int rr = 0; rr < 4; ++rr) {
                out[(size_t)(trow + rr) * (BB * NH) + (size_t)b * NH + h] =
                    acc[mt][nt][rr] + bias;
            }
        }
    }
}

// ---------------------------------------------------------------------------
// K2 v9 (round-6 verified, 797 µs) — fallback when ws too small.
// ---------------------------------------------------------------------------
#define RKT 12
#define LKT 4

__global__ __launch_bounds__(1024, 4) void rnn_scan_v9(
    const float* __restrict__ Waa, float* __restrict__ out)
{
    __shared__ uint4 wlds[LKT * 2][1024];
    __shared__ __align__(16) unsigned short a_h[2][NH];

    const int tid = threadIdx.x;
    const int b   = blockIdx.x;
    const int w   = tid >> 6;
    const int l   = tid & 63;
    const int q   = l >> 4;
    const int c0  = w * 32 + (l & 15);
    const int c1  = c0 + 16;

    uint4 br0[RKT], br1[RKT];
#pragma unroll
    for (int kk = 0; kk < RKT; ++kk) {
        const int kb = kk * 32 + 8 * q;
        br0[kk] = mkbfrag(Waa, kb, c0);
        br1[kk] = mkbfrag(Waa, kb, c1);
    }
#pragma unroll
    for (int kk = 0; kk < LKT; ++kk) {
        const int kb = (RKT + kk) * 32 + 8 * q;
        wlds[kk * 2 + 0][tid] = mkbfrag(Waa, kb, c0);
        wlds[kk * 2 + 1][tid] = mkbfrag(Waa, kb, c1);
    }

    if (tid < 256) *(unsigned*)&a_h[0][tid * 2] = 0u;
    __syncthreads();

    const float* ub0 = out + (size_t)b * NH + c0;
    const float* ub1 = out + (size_t)b * NH + c1;
    float u0 = ub0[0], u1 = ub1[0];

    for (int t = 0; t < TT; ++t) {
        const int tn = (t + 1 < TT) ? (t + 1) : (TT - 1);
        float un0 = ub0[(size_t)tn * (BB * NH)];
        float un1 = ub1[(size_t)tn * (BB * NH)];

        const unsigned short* ac = a_h[t & 1];
        f32x4 acc0 = {}, acc1 = {};
#pragma unroll
        for (int kk = 0; kk < 16; ++kk) {
            uint4 av = *(const uint4*)&ac[kk * 32 + q * 8];
            half8_t A = __builtin_bit_cast(half8_t, av);
            uint4 b0, b1;
            if (kk < RKT) { b0 = br0[kk]; b1 = br1[kk]; }
            else { b0 = wlds[(kk - RKT) * 2 + 0][tid]; b1 = wlds[(kk - RKT) * 2 + 1][tid]; }
            acc0 = mfma16(A, b0, acc0);
            acc1 = mfma16(A, b1, acc1);
        }

        float an0 = tanh_fast(u0 + acc0[0]);
        float an1 = tanh_fast(u1 + acc1[0]);

        unsigned short* an = a_h[(t + 1) & 1];
        if (l < 16) {
            an[c0] = __builtin_bit_cast(unsigned short, (_Float16)an0);
            an[c1] = __builtin_bit_cast(unsigned short, (_Float16)an1);
            out[(size_t)t * (BB * NH) + (size_t)b * NH + c0] = an0;
            out[(size_t)t * (BB * NH) + (size_t)b * NH + c1] = an1;
        }
        u0 = un0;
        u1 = un1;
        __builtin_amdgcn_s_waitcnt(0xC07F);
        __builtin_amdgcn_s_barrier();
    }
}

// ---------------------------------------------------------------------------
// K2 v11 (2 CUs per batch): 128 blocks x 512 thr. Block (half=bid>>6,
// b=bid&63) owns cols [256*half, 256*half+256): 8 waves x 2 N-tiles x 16
// K-tiles = 256 MFMA/step (HALF of v9's per-CU pipe load). Local K-half of
// a_t from LDS (dbuf); remote K-half from the partner block via workspace:
//   writer: u16 stores of its a_{t+1} cols -> vmcnt(0)+barrier -> tid0
//           RELEASE flag store (flag = t+1).
//   reader: ACQUIRE spin (flag >= t, fuel-bounded), remote uint4 A-frags
//           from global — latency hidden under the local MFMA phase.
// Slot/flag race-freedom: we overwrite slot[(t+1)&1] only after observing
// flag >= t, which implies the partner has finished reading that slot.
// Replay-safe: flags/rem zeroed by pack_f16 in the same graph; stale flags
// (counter-replay without pack) only skip waits, never deadlock.
// ---------------------------------------------------------------------------
#define RKT_R 4   // remote K-tiles in registers
#define LKT_R 4   // remote K-tiles in LDS

__global__ __launch_bounds__(512, 2) void rnn_scan_v11(
    const float* __restrict__ Waa, float* __restrict__ out,
    unsigned short* __restrict__ rem, unsigned* __restrict__ flags)
{
    __shared__ uint4 wldsB[LKT_R * 2][512];          // 64 KB remote B-frags
    __shared__ __align__(16) unsigned short a_loc[2][256];   // local half, dbuf

    const int tid  = threadIdx.x;
    const int bid  = blockIdx.x;
    const int half = bid >> 6;
    const int b    = bid & 63;
    const int w    = tid >> 6;
    const int l    = tid & 63;
    const int q    = l >> 4;
    const int cb   = half * 256;
    const int c0   = cb + w * 32 + (l & 15);
    const int c1   = c0 + 16;
    const int kkL0 = half * 8;          // local K-tiles [kkL0, kkL0+8)
    const int kkR0 = 8 - half * 8;      // remote K-tiles [kkR0, kkR0+8)

    // ---- preamble: B-frags. Local 8 K-tiles in reg; remote 4 reg + 4 LDS.
    uint4 bl0[8], bl1[8], br0[RKT_R], br1[RKT_R];
#pragma unroll
    for (int i = 0; i < 8; ++i) {
        const int kb = (kkL0 + i) * 32 + 8 * q;
        bl0[i] = mkbfrag(Waa, kb, c0);
        bl1[i] = mkbfrag(Waa, kb, c1);
    }
#pragma unroll
    for (int i = 0; i < RKT_R; ++i) {
        const int kb = (kkR0 + i) * 32 + 8 * q;
        br0[i] = mkbfrag(Waa, kb, c0);
        br1[i] = mkbfrag(Waa, kb, c1);
    }
#pragma unroll
    for (int i = 0; i < LKT_R; ++i) {
        const int kb = (kkR0 + RKT_R + i) * 32 + 8 * q;
        wldsB[i * 2 + 0][tid] = mkbfrag(Waa, kb, c0);
        wldsB[i * 2 + 1][tid] = mkbfrag(Waa, kb, c1);
    }
    if (tid < 128) *(unsigned*)&a_loc[0][tid * 2] = 0u;   // a_0 local = 0
    __syncthreads();

    unsigned* flagMine  = &flags[(b * 2 + half) * 32];
    unsigned* flagOther = &flags[(b * 2 + (1 - half)) * 32];

    const float* ub0 = out + (size_t)b * NH + c0;
    const float* ub1 = out + (size_t)b * NH + c1;
    float u0 = ub0[0], u1 = ub1[0];

    for (int t = 0; t < TT; ++t) {
        const int tn = (t + 1 < TT) ? (t + 1) : (TT - 1);
        float un0 = ub0[(size_t)tn * (BB * NH)];
        float un1 = ub1[(size_t)tn * (BB * NH)];

        // ---- spin: partner's a_t published? (fuel-bounded, acquire) ----
        unsigned fuel = 1u << 24;
        while (__hip_atomic_load(flagOther, __ATOMIC_ACQUIRE,
                                 __HIP_MEMORY_SCOPE_AGENT) < (unsigned)t) {
            if (--fuel == 0) break;
            __builtin_amdgcn_s_sleep(2);
        }

        // ---- issue remote A-frag loads (latency hidden by local phase) ----
        const unsigned short* ar = rem + ((size_t)b * 2 + (t & 1)) * 512;
        uint4 avr[8];
#pragma unroll
        for (int i = 0; i < 8; ++i)
            avr[i] = *(const uint4*)&ar[(kkR0 + i) * 32 + q * 8];

        // ---- local phase: a from LDS, 8 K-tiles, 8-deep chains ----
        const unsigned short* ac = a_loc[t & 1];
        f32x4 aL0 = {}, aL1 = {}, aR0 = {}, aR1 = {};
#pragma unroll
        for (int i = 0; i < 8; ++i) {
            uint4 av = *(const uint4*)&ac[i * 32 + q * 8];
            half8_t A = __builtin_bit_cast(half8_t, av);
            aL0 = mfma16(A, bl0[i], aL0);
            aL1 = mfma16(A, bl1[i], aL1);
        }
        // ---- remote phase: 4 reg + 4 LDS B-frags ----
#pragma unroll
        for (int i = 0; i < RKT_R; ++i) {
            half8_t A = __builtin_bit_cast(half8_t, avr[i]);
            aR0 = mfma16(A, br0[i], aR0);
            aR1 = mfma16(A, br1[i], aR1);
        }
#pragma unroll
        for (int i = 0; i < LKT_R; ++i) {
            half8_t A = __builtin_bit_cast(half8_t, avr[RKT_R + i]);
            aR0 = mfma16(A, wldsB[i * 2 + 0][tid], aR0);
            aR1 = mfma16(A, wldsB[i * 2 + 1][tid], aR1);
        }

        float an0 = tanh_fast(u0 + (aL0[0] + aR0[0]));
        float an1 = tanh_fast(u1 + (aL1[0] + aR1[0]));

        // ---- publish a_{t+1}: LDS local + global own half ----
        unsigned short* al = a_loc[(t + 1) & 1];
        unsigned short* aw = rem + ((size_t)b * 2 + ((t + 1) & 1)) * 512;
        unsigned short h0b = __builtin_bit_cast(unsigned short, (_Float16)an0);
        unsigned short h1b = __builtin_bit_cast(unsigned short, (_Float16)an1);
        if (l < 16) {
            al[c0 - cb] = h0b;
            al[c1 - cb] = h1b;
            aw[c0] = h0b;
            aw[c1] = h1b;
        }
        u0 = un0;
        u1 = un1;
        __builtin_amdgcn_s_waitcnt(0);        // drain vm + lgkm (aw committed)
        __builtin_amdgcn_s_barrier();
        if (tid == 0)
            __hip_atomic_store(flagMine, (unsigned)(t + 1), __ATOMIC_RELEASE,
                               __HIP_MEMORY_SCOPE_AGENT);
        if (l < 16) {                         // fire-and-forget output
            out[(size_t)t * (BB * NH) + (size_t)b * NH + c0] = an0;
            out[(size_t)t * (BB * NH) + (size_t)b * NH + c1] = an1;
        }
    }
}

extern "C" void kernel_launch(void* const* d_in, const int* in_sizes, int n_in,
                              void* d_out, int out_size, void* d_ws, size_t ws_size,
                              hipStream_t stream) {
    const float* X   = (const float*)d_in[0];
    const float* Wax = (const float*)d_in[1];
    const float* Waa = (const float*)d_in[2];
    const float* bx  = (const float*)d_in[3];
    const float* ba  = (const float*)d_in[4];
    float* out = (float*)d_out;

    const size_t xp_dw = (size_t)BB * (NIN / 2) * TT;   // 8,388,608
    const size_t wp_dw = (size_t)(NIN / 2) * NH;        // 131,072
    const size_t need  = (xp_dw + wp_dw + REM_DW + FLG_DW) * sizeof(unsigned);

    if (ws_size >= need) {
        unsigned* base = (unsigned*)d_ws;
        unsigned* Xp   = base;
        unsigned* Wp   = base + xp_dw;
        unsigned* zb   = base + xp_dw + wp_dw;
        unsigned short* rem = (unsigned short*)zb;
        unsigned* flags     = zb + REM_DW;
        const int npack = (NX4 + NW4 + NZ4 + 255) / 256;
        pack_f16<<<npack, 256, 0, stream>>>(X, Wax, Xp, Wp, zb);
        dim3 g1(NH / 128, TT / 128, BB);
        inp_proj_mfma_pk<<<g1, 256, 0, stream>>>(Xp, Wp, bx, ba, out);
        rnn_scan_v11<<<128, 512, 0, stream>>>(Waa, out, rem, flags);
    } else {
        dim3 g1(NH / 128, TT / 128, BB);
        inp_proj_mfma<<<g1, 256, 0, stream>>>(X, Wax, bx, ba, out);
        rnn_scan_v9<<<BB, 1024, 0, stream>>>(Waa, out);
    }
}